// Round 4
// baseline (120.039 us; speedup 1.0000x reference)
//
#include <hip/hip_runtime.h>

// Problem: y = x * exp(S)[None,:]  (B=65536, D=1024, f32)
//          det_out = original_det + sum(S)
// d_out layout: [ y (B*D f32) | det_out (B f32) ]
//
// Single fused kernel, blockDim.x == D/4 == 256 so thread t owns column block
// t of every row -> exp(S) factor lives in 4 registers, no LDS on hot path.
// 2048 blocks = 32 waves/CU, 32 main iterations/lane (amortizes prologue),
// manual 4x unroll for memory-level parallelism.

typedef float f32x4 __attribute__((ext_vector_type(4)));

__global__ __launch_bounds__(256) void fused_kernel(
    const f32x4* __restrict__ x,
    const f32x4* __restrict__ det,
    const f32x4* __restrict__ S4,      // D/4 float4
    f32x4* __restrict__ y,
    f32x4* __restrict__ det_out,
    size_t nvec,                       // B*D/4
    int    dvec)                       // B/4
{
    const int tid = threadIdx.x;

    // --- per-thread exp(S) factor (thread t owns columns 4t..4t+3) ---
    f32x4 s4 = S4[tid];
    f32x4 e4;
    e4.x = expf(s4.x);
    e4.y = expf(s4.y);
    e4.z = expf(s4.z);
    e4.w = expf(s4.w);

    // --- block-redundant log_det = sum(S) (cheap: 6 shuffle+add) ---
    __shared__ float red[4];
    float local = s4.x + s4.y + s4.z + s4.w;
    for (int off = 32; off > 0; off >>= 1)
        local += __shfl_down(local, off, 64);
    if ((tid & 63) == 0) red[tid >> 6] = local;
    __syncthreads();
    const float log_det = red[0] + red[1] + red[2] + red[3];

    // --- main stream: y = x * e4, 4x unrolled for MLP ---
    const size_t stride  = (size_t)gridDim.x * 256;   // multiple of 256
    const size_t stride4 = stride * 4;
    size_t v = (size_t)blockIdx.x * 256 + tid;
    for (; v + 3 * stride < nvec; v += stride4) {
        f32x4 a = __builtin_nontemporal_load(&x[v]);
        f32x4 b = __builtin_nontemporal_load(&x[v + stride]);
        f32x4 c = __builtin_nontemporal_load(&x[v + 2 * stride]);
        f32x4 d = __builtin_nontemporal_load(&x[v + 3 * stride]);
        __builtin_nontemporal_store(a * e4, &y[v]);
        __builtin_nontemporal_store(b * e4, &y[v + stride]);
        __builtin_nontemporal_store(c * e4, &y[v + 2 * stride]);
        __builtin_nontemporal_store(d * e4, &y[v + 3 * stride]);
    }
    for (; v < nvec; v += stride) {
        f32x4 xv = __builtin_nontemporal_load(&x[v]);
        __builtin_nontemporal_store(xv * e4, &y[v]);
    }

    // --- det tail: det_out = det + log_det (256 KB r + 256 KB w) ---
    for (size_t i = (size_t)blockIdx.x * 256 + tid; i < (size_t)dvec; i += stride) {
        f32x4 d = __builtin_nontemporal_load(&det[i]);
        __builtin_nontemporal_store(d + log_det, &det_out[i]);
    }
}

extern "C" void kernel_launch(void* const* d_in, const int* in_sizes, int n_in,
                              void* d_out, int out_size, void* d_ws, size_t ws_size,
                              hipStream_t stream) {
    const float* x   = (const float*)d_in[0];
    const float* det = (const float*)d_in[1];
    const float* S   = (const float*)d_in[2];

    const int xN = in_sizes[0];      // B*D = 67108864
    const int B  = in_sizes[1];      // 65536

    float* y_out   = (float*)d_out;
    float* det_out = (float*)d_out + (size_t)xN;

    size_t nvec = (size_t)xN / 4;    // 16,777,216 float4
    int    dvec = B / 4;             // 16,384 float4

    // 2048 blocks x 256 threads = 32 waves/CU; 32 main float4 per lane.
    int blocks = 2048;

    fused_kernel<<<blocks, 256, 0, stream>>>(
        (const f32x4*)x, (const f32x4*)det, (const f32x4*)S,
        (f32x4*)y_out, (f32x4*)det_out, nvec, dvec);
}

// Round 5
// 91.808 us; speedup vs baseline: 1.3075x; 1.3075x over previous
//
#include <hip/hip_runtime.h>

// Problem: y = x * exp(S)[None,:]  (B=65536, D=1024, f32)
//          det_out = original_det + sum(S)
// d_out layout: [ y (B*D f32) | det_out (B f32) ]
//
// 8192 blocks x 256 threads. Each block owns a CONTIGUOUS 2048-float4 chunk
// (32 KB read + 32 KB write), 8 wave-strided iterations. All 8 loads are
// issued before the exp/log_det prologue so HBM latency overlaps the VALU
// prologue; 8 outstanding loads/lane for memory-level parallelism.
// blockDim == D/4 == 256 and chunk is a multiple of 256 -> thread t always
// touches column block ((base + t) & 255): with base % 256 == 0 that is t,
// so its exp factor is 4 registers.

typedef float f32x4 __attribute__((ext_vector_type(4)));

__global__ __launch_bounds__(256) void fused_kernel(
    const f32x4* __restrict__ x,
    const f32x4* __restrict__ det,
    const f32x4* __restrict__ S4,      // D/4 float4
    f32x4* __restrict__ y,
    f32x4* __restrict__ det_out,
    size_t nvec,                       // B*D/4
    int    dvec)                       // B/4
{
    const int tid = threadIdx.x;
    const size_t base = (size_t)blockIdx.x * 2048 + tid;

    // --- issue all 8 x-loads first (independent of S) ---
    f32x4 r0, r1, r2, r3, r4, r5, r6, r7;
    bool full = (base + 7 * 256) < nvec;
    if (full) {
        r0 = __builtin_nontemporal_load(&x[base + 0 * 256]);
        r1 = __builtin_nontemporal_load(&x[base + 1 * 256]);
        r2 = __builtin_nontemporal_load(&x[base + 2 * 256]);
        r3 = __builtin_nontemporal_load(&x[base + 3 * 256]);
        r4 = __builtin_nontemporal_load(&x[base + 4 * 256]);
        r5 = __builtin_nontemporal_load(&x[base + 5 * 256]);
        r6 = __builtin_nontemporal_load(&x[base + 6 * 256]);
        r7 = __builtin_nontemporal_load(&x[base + 7 * 256]);
    }

    // --- per-thread exp(S) factor (overlaps the load latency) ---
    f32x4 s4 = S4[tid];
    f32x4 e4;
    e4.x = expf(s4.x);
    e4.y = expf(s4.y);
    e4.z = expf(s4.z);
    e4.w = expf(s4.w);

    // --- block-redundant log_det = sum(S) ---
    __shared__ float red[4];
    float local = s4.x + s4.y + s4.z + s4.w;
    for (int off = 32; off > 0; off >>= 1)
        local += __shfl_down(local, off, 64);
    if ((tid & 63) == 0) red[tid >> 6] = local;
    __syncthreads();
    const float log_det = red[0] + red[1] + red[2] + red[3];

    // --- main: multiply + store ---
    if (full) {
        __builtin_nontemporal_store(r0 * e4, &y[base + 0 * 256]);
        __builtin_nontemporal_store(r1 * e4, &y[base + 1 * 256]);
        __builtin_nontemporal_store(r2 * e4, &y[base + 2 * 256]);
        __builtin_nontemporal_store(r3 * e4, &y[base + 3 * 256]);
        __builtin_nontemporal_store(r4 * e4, &y[base + 4 * 256]);
        __builtin_nontemporal_store(r5 * e4, &y[base + 5 * 256]);
        __builtin_nontemporal_store(r6 * e4, &y[base + 6 * 256]);
        __builtin_nontemporal_store(r7 * e4, &y[base + 7 * 256]);
    } else {
        // generic tail (not hit for B=65536, D=1024 with 8192 blocks)
        for (size_t v = base; v < nvec; v += 256) {
            f32x4 xv = __builtin_nontemporal_load(&x[v]);
            __builtin_nontemporal_store(xv * e4, &y[v]);
        }
    }

    // --- det tail: first 64 blocks, one float4 per thread ---
    size_t di = (size_t)blockIdx.x * 256 + tid;
    if (di < (size_t)dvec) {
        f32x4 d = __builtin_nontemporal_load(&det[di]);
        __builtin_nontemporal_store(d + log_det, &det_out[di]);
    }
}

extern "C" void kernel_launch(void* const* d_in, const int* in_sizes, int n_in,
                              void* d_out, int out_size, void* d_ws, size_t ws_size,
                              hipStream_t stream) {
    const float* x   = (const float*)d_in[0];
    const float* det = (const float*)d_in[1];
    const float* S   = (const float*)d_in[2];

    const int xN = in_sizes[0];      // B*D = 67108864
    const int B  = in_sizes[1];      // 65536

    float* y_out   = (float*)d_out;
    float* det_out = (float*)d_out + (size_t)xN;

    size_t nvec = (size_t)xN / 4;    // 16,777,216 float4
    int    dvec = B / 4;             // 16,384 float4

    // 8192 blocks x 2048 float4/block covers nvec exactly.
    int blocks = (int)((nvec + 2047) / 2048);

    fused_kernel<<<blocks, 256, 0, stream>>>(
        (const f32x4*)x, (const f32x4*)det, (const f32x4*)S,
        (f32x4*)y_out, (f32x4*)det_out, nvec, dvec);
}